// Round 6
// baseline (267.016 us; speedup 1.0000x reference)
//
#include <hip/hip_runtime.h>

#define NQ   65536
#define NC   4096
#define SOUT 64
#define NR   4                 // monomials (DEGREE=1, NDIM=3)
#define KTOT (NC + 64)         // 4160: coeffs padded with zeros to 4160
#define BM   64                // 4 waves x 16 q-rows
#define NCH  (NC / 64)         // 64 r2 chunks of BK=64

typedef float    f32x4 __attribute__((ext_vector_type(4)));
typedef _Float16 f16x8 __attribute__((ext_vector_type(8)));
typedef __fp16   h16x2 __attribute__((ext_vector_type(2)));
typedef unsigned uint4v __attribute__((ext_vector_type(4)));

// ---------------- pre-kernels (write d_ws; deterministic every call) ---------

// Bt[n][k] = f16(coeffs[k][n]) for k < NC+NR, else 0.  (64 x 4160)
__global__ void prep_bt(const float* __restrict__ coeffs, _Float16* __restrict__ bt) {
    const int k = blockIdx.x * 256 + threadIdx.x;
    const int n = blockIdx.y;
    if (k >= KTOT) return;
    const float v = (k < NC + NR) ? coeffs[(size_t)k * SOUT + n] : 0.0f;
    bt[(size_t)n * KTOT + k] = (_Float16)v;
}

// Ye[k] = [-2y0, -2y1, -2y2, 1, |y|^2, 0,0,0]  (f16, 16 B rows)
__global__ void prep_ye(const float* __restrict__ y, _Float16* __restrict__ ye) {
    const int k = blockIdx.x * 256 + threadIdx.x;
    if (k >= NC) return;
    const float a = y[k * 3 + 0], b = y[k * 3 + 1], c = y[k * 3 + 2];
    const float s = a * a + b * b + c * c;
    f16x8 r = {(_Float16)(-2.0f * a), (_Float16)(-2.0f * b), (_Float16)(-2.0f * c),
               (_Float16)1.0f, (_Float16)s,
               (_Float16)0.0f, (_Float16)0.0f, (_Float16)0.0f};
    *(f16x8*)(ye + (size_t)k * 8) = r;
}

// ---------------- main kernel ------------------------------------------------
// No LDS, no barriers. Each wave owns 16 q-rows x all 64 out-cols.
// r2 via mfma(A=Ye-perm, B=Xe); center permutation kappa(kt,rho) =
// (kt&1)*32 + (rho>>2)*8 + (kt>>1)*4 + (rho&3) makes the r2 outputs land
// exactly in out-GEMM A-fragment layout: afrag[kk] = {w[kk].x, w[kk].y,
// w[kk+2].x, w[kk+2].y}. Pure register concatenation, zero data movement.
__launch_bounds__(256)
__global__ void rbf_mfma4(const float* __restrict__ x,
                          const _Float16* __restrict__ ye,
                          const float* __restrict__ shift,
                          const float* __restrict__ scale,
                          const _Float16* __restrict__ bt,
                          float* __restrict__ out) {
    const int t    = threadIdx.x;
    const int wave = t >> 6;
    const int lane = t & 63;
    const int l15  = lane & 15;
    const int lg   = lane >> 4;
    const int qb   = blockIdx.x * BM + wave * 16;   // this wave's 16 q-rows
    const int q    = qb + l15;

    // Xe B-fragment: lg==0 lanes hold [x0,x1,x2,xsq,1,0,0,0], else 0
    f16x8 xef = {};
    {
        const float a = x[q * 3 + 0], b = x[q * 3 + 1], c = x[q * 3 + 2];
        if (lg == 0) {
            xef[0] = (_Float16)a; xef[1] = (_Float16)b; xef[2] = (_Float16)c;
            xef[3] = (_Float16)(a * a + b * b + c * c); xef[4] = (_Float16)1.0f;
        }
    }

    // poly A-frag dwords {1,xh0},{xh1,xh2} for row q (used by lg==0 lanes)
    uint2 poly01;
    {
        const float a = x[q * 3 + 0], b = x[q * 3 + 1], c = x[q * 3 + 2];
        h16x2 p0 = __builtin_amdgcn_cvt_pkrtz(1.0f, (a - shift[0]) / scale[0]);
        h16x2 p1 = __builtin_amdgcn_cvt_pkrtz((b - shift[1]) / scale[1],
                                              (c - shift[2]) / scale[2]);
        poly01.x = __builtin_bit_cast(unsigned, p0);
        poly01.y = __builtin_bit_cast(unsigned, p1);
    }

    // ye row for r2-tile kt, A-row rho=l15: kappa = (kt&1)*32+(l15>>2)*8+(kt>>1)*4+(l15&3)
    const _Float16* yeb = ye + ((size_t)((l15 >> 2) * 8 + (l15 & 3))) * 8;

    // bt fragment base (elements): row n = nf*16+l15, k-offset lg*8
    const _Float16* btb = bt + (size_t)l15 * KTOT + lg * 8;

    f32x4 acc[4] = {};   // [nf]

    for (int ch = 0; ch < NCH; ++ch) {
        // ---- B fragments (L2/L1-hot; all 4 waves in a CU share the chunk) ----
        f16x8 bfrag[4][2];
        #pragma unroll
        for (int nf = 0; nf < 4; ++nf)
            #pragma unroll
            for (int kk = 0; kk < 2; ++kk)
                bfrag[nf][kk] = *(const f16x8*)(
                    btb + (size_t)nf * 16 * KTOT + ch * 64 + kk * 32);

        // ---- r2 tiles + f-eval, permuted so outputs are A-frag-ready ----
        uint2 w[4];
        #pragma unroll
        for (int kt = 0; kt < 4; ++kt) {
            const f16x8 yef = *(const f16x8*)(
                yeb + ch * 512 + (kt & 1) * 256 + (kt >> 1) * 32);
            f32x4 z = {};
            const f32x4 r2 = __builtin_amdgcn_mfma_f32_16x16x32_f16(
                yef, xef, z, 0, 0, 0);
            float f[4];
            #pragma unroll
            for (int r = 0; r < 4; ++r) {
                const float rc = fmaxf(r2[r], 1e-37f);
                f[r] = 0.34657359f * rc * __log2f(rc);
            }
            h16x2 h0 = __builtin_amdgcn_cvt_pkrtz(f[0], f[1]);
            h16x2 h1 = __builtin_amdgcn_cvt_pkrtz(f[2], f[3]);
            w[kt].x = __builtin_bit_cast(unsigned, h0);
            w[kt].y = __builtin_bit_cast(unsigned, h1);
        }
        const uint4v a0 = {w[0].x, w[0].y, w[2].x, w[2].y};
        const uint4v a1 = {w[1].x, w[1].y, w[3].x, w[3].y};
        const f16x8 af0 = __builtin_bit_cast(f16x8, a0);
        const f16x8 af1 = __builtin_bit_cast(f16x8, a1);

        // ---- out-GEMM MFMAs ----
        #pragma unroll
        for (int nf = 0; nf < 4; ++nf) {
            acc[nf] = __builtin_amdgcn_mfma_f32_16x16x32_f16(
                af0, bfrag[nf][0], acc[nf], 0, 0, 0);
            acc[nf] = __builtin_amdgcn_mfma_f32_16x16x32_f16(
                af1, bfrag[nf][1], acc[nf], 0, 0, 0);
        }
    }

    // ---- poly tail: one kk=0 MFMA; A = [1,xh0,xh1,xh2,0...] on lg==0 ----
    {
        uint4v ap = {};
        if (lg == 0) { ap.x = poly01.x; ap.y = poly01.y; }
        const f16x8 afp = __builtin_bit_cast(f16x8, ap);
        #pragma unroll
        for (int nf = 0; nf < 4; ++nf) {
            const f16x8 bp = *(const f16x8*)(btb + (size_t)nf * 16 * KTOT + NC);
            acc[nf] = __builtin_amdgcn_mfma_f32_16x16x32_f16(
                afp, bp, acc[nf], 0, 0, 0);
        }
    }

    // ---- epilogue: C/D col=lane&15 (n), row=lg*4+r (q) ----
    #pragma unroll
    for (int nf = 0; nf < 4; ++nf)
        #pragma unroll
        for (int r = 0; r < 4; ++r)
            out[(size_t)(qb + lg * 4 + r) * SOUT + nf * 16 + l15] = acc[nf][r];
}

// ---------------- fallback (round-1 kernel) if d_ws too small ----------------
__launch_bounds__(256)
__global__ void rbf_tps_fallback(const float* __restrict__ x,
                                 const float* __restrict__ y,
                                 const float* __restrict__ coeffs,
                                 const float* __restrict__ shift,
                                 const float* __restrict__ scale,
                                 float* __restrict__ out) {
    __shared__ float4 ytile[NC];
    const int tid = threadIdx.x;
    for (int j = tid; j < NC; j += 256) {
        const float a = y[j * 3], b = y[j * 3 + 1], c = y[j * 3 + 2];
        ytile[j] = make_float4(a, b, c, a * a + b * b + c * c);
    }
    __syncthreads();
    const int q = blockIdx.x * 256 + tid;
    const float x0 = x[q * 3], x1 = x[q * 3 + 1], x2 = x[q * 3 + 2];
    const float xsq = x0 * x0 + x1 * x1 + x2 * x2;
    const float xh0 = (x0 - shift[0]) / scale[0];
    const float xh1 = (x1 - shift[1]) / scale[1];
    const float xh2 = (x2 - shift[2]) / scale[2];
    float acc[SOUT];
    {
        const float* c0 = &coeffs[(size_t)(NC + 0) * SOUT];
        const float* c1 = &coeffs[(size_t)(NC + 1) * SOUT];
        const float* c2 = &coeffs[(size_t)(NC + 2) * SOUT];
        const float* c3 = &coeffs[(size_t)(NC + 3) * SOUT];
        #pragma unroll
        for (int s = 0; s < SOUT; ++s)
            acc[s] = c0[s] + xh0 * c1[s] + xh1 * c2[s] + xh2 * c3[s];
    }
    #pragma unroll 2
    for (int j = 0; j < NC; ++j) {
        const float4 yj = ytile[j];
        const float dot = x0 * yj.x + x1 * yj.y + x2 * yj.z;
        float r2 = fmaf(-2.0f, dot, xsq + yj.w);
        r2 = fmaxf(r2, 0.0f);
        const float f = 0.5f * r2 * __logf(fmaxf(r2, 1e-37f));
        const float* __restrict__ cj = &coeffs[(size_t)j * SOUT];
        #pragma unroll
        for (int s = 0; s < SOUT; ++s) acc[s] = fmaf(f, cj[s], acc[s]);
    }
    float4* o4 = (float4*)&out[(size_t)q * SOUT];
    #pragma unroll
    for (int s = 0; s < SOUT / 4; ++s)
        o4[s] = make_float4(acc[4 * s], acc[4 * s + 1], acc[4 * s + 2], acc[4 * s + 3]);
}

extern "C" void kernel_launch(void* const* d_in, const int* in_sizes, int n_in,
                              void* d_out, int out_size, void* d_ws, size_t ws_size,
                              hipStream_t stream) {
    const float* x      = (const float*)d_in[0];
    const float* y      = (const float*)d_in[1];
    const float* coeffs = (const float*)d_in[2];
    const float* shift  = (const float*)d_in[3];
    const float* scale  = (const float*)d_in[4];
    float* out = (float*)d_out;

    const size_t bt_bytes = (size_t)SOUT * KTOT * sizeof(_Float16);  // 532,480
    const size_t ye_bytes = (size_t)NC * 8 * sizeof(_Float16);       //  65,536

    if (ws_size >= bt_bytes + ye_bytes) {
        _Float16* bt  = (_Float16*)d_ws;
        _Float16* yep = (_Float16*)((char*)d_ws + bt_bytes);
        hipLaunchKernelGGL(prep_bt, dim3((KTOT + 255) / 256, SOUT), dim3(256),
                           0, stream, coeffs, bt);
        hipLaunchKernelGGL(prep_ye, dim3((NC + 255) / 256), dim3(256),
                           0, stream, y, yep);
        hipLaunchKernelGGL(rbf_mfma4, dim3(NQ / BM), dim3(256), 0, stream,
                           x, yep, shift, scale, bt, out);
    } else {
        hipLaunchKernelGGL(rbf_tps_fallback, dim3(NQ / 256), dim3(256),
                           0, stream, x, y, coeffs, shift, scale, out);
    }
}